// Round 14
// baseline (5918.865 us; speedup 1.0000x reference)
//
#include <hip/hip_runtime.h>
#include <hip/hip_bf16.h>

#define B_   64
#define S_   1024
#define D_   512
#define H_   512
#define NWG  256    // 1 wave per WG -> 1 per CU; 4 row-cohorts x 64 col-slices
#define NCS  64     // column slices
#define HCW  8      // h-columns per col-slice
#define NT   64

typedef __attribute__((ext_vector_type(8))) short short8;
typedef __attribute__((ext_vector_type(4))) float f32x4;

// Swizzled byte offset into the LDS W tile: [gc][k] bf16, row = 2048 B.
__device__ __forceinline__ int wl_byte(int gc, int k) {
  return ((gc << 11) + (k << 1)) ^ ((gc & 7) << 4);
}
__device__ __forceinline__ float sigm(float v) { return 1.0f / (1.0f + __expf(-v)); }
__device__ __forceinline__ float tanh_(float v) { return 1.0f - 2.0f / (__expf(2.0f * v) + 1.0f); }
__device__ __forceinline__ short f2bf(float f) {
  __hip_bfloat16 h = __float2bfloat16(f);
  short s;
  __builtin_memcpy(&s, &h, 2);
  return s;
}

union U128 { unsigned long long u[2]; unsigned int w[4]; short8 s; };

// DEVICE-scope (sc1) 16B store: bypasses the XCD-private L2 (the non-coherent
// boundary), resolves at the on-die LLC. Single transaction -> record atomic
// (MUST stay one dwordx4: tag bit1 lives in col4).
__device__ __forceinline__ void store_b128_dev(void* p, short8 v) {
  asm volatile("global_store_dwordx4 %0, %1, off sc1" :: "v"(p), "v"(v) : "memory");
}

// Async global->LDS, 16B per lane; LDS dest = uniform base + lane*16.
__device__ __forceinline__ void gload_lds16(const short* g, short* l) {
  __builtin_amdgcn_global_load_lds(
      (const __attribute__((address_space(1))) unsigned int*)(const void*)g,
      (__attribute__((address_space(3))) unsigned int*)l, 16, 0, 0);
}

// ---------------------------------------------------------------------------
// Prep: xb = bf16(x), same [B][S][D] layout.
// ---------------------------------------------------------------------------
__global__ __launch_bounds__(256, 1) void lstm_xprep(
    const float* __restrict__ xg, short* __restrict__ xb)
{
  const size_t i = ((size_t)blockIdx.x * 256 + threadIdx.x) * 8;
  f32x4 a = *(const f32x4*)(xg + i);
  f32x4 b = *(const f32x4*)(xg + i + 4);
  short8 v;
#pragma unroll
  for (int j = 0; j < 4; ++j) { v[j] = f2bf(a[j]); v[4 + j] = f2bf(b[j]); }
  *(short8*)(xb + i) = v;
}

// Record format (16B, one per (row, cs)): 8 bf16 = one MFMA A-fragment.
// Step tag (t mod 4) embedded as LSBs of col0 (bit0) and col4 (bit1).
// Poll-passing induction bounds slot staleness to {t, t-2}; bit1 separates.

template<int USE_XB>
__global__ __launch_bounds__(NT, 1) void lstm_persist(
    const float* __restrict__ xg, const short* __restrict__ xb,
    const float* __restrict__ Wf, const float* __restrict__ bfv,
    const float* __restrict__ Wi, const float* __restrict__ biv,
    const float* __restrict__ Wc, const float* __restrict__ bcv,
    const float* __restrict__ Wo, const float* __restrict__ bov,
    float* __restrict__ out,
    char* __restrict__ hbc)   // [2][64 rows][64 cs][16B] tagged fragment records
{
  __shared__ short Wl[32 * 1024];    // 64 KB: W slice, [gc][k] bf16, swizzled
  __shared__ short Xl[2][8192];      // 32 KB: x(t) double buffer, [ks][lane*8]

  const int tid  = threadIdx.x;
  const int wg   = blockIdx.x;
  const int cs   = wg >> 2;          // column slice 0..63
  const int rc   = wg & 3;           // row cohort 0..3 (16 batch rows)
  const int lane = tid;              // single wave

  // ---- one-time: stage this WG's W slice (transposed to [gc][k], bf16) ----
  {
    const float* Wg4[4] = {Wf, Wi, Wc, Wo};
    const int gc  = tid >> 1;        // 0..31
    const int seg = tid & 1;         // k half of 512
    const float* Wsrc = Wg4[gc >> 3];
    const int col = cs * HCW + (gc & 7);
    for (int kk = 0; kk < 512; ++kk) {
      const int k = seg * 512 + kk;
      *(short*)((char*)Wl + wl_byte(gc, k)) = f2bf(Wsrc[(size_t)k * H_ + col]);
    }
  }

  // Transposed-C lane mapping: lane&15 = batch row, (lane>>4)*4+reg = gatecol.
  const int q    = lane >> 4;        // 0..3
  const int rr   = lane & 15;        // batch row within wave tile
  const int c0   = (q & 1) << 2;     // col-quad base within slice's 8 cols
  const int colq = cs * HCW + c0;    // global col-quad base
  float bF4[4], bI4[4], bG4[4], bO4[4];
#pragma unroll
  for (int r = 0; r < 4; ++r) {
    bF4[r] = bfv[colq + r]; bI4[r] = biv[colq + r];
    bG4[r] = bcv[colq + r]; bO4[r] = bov[colq + r];
  }

  const int rowb = (rc << 4) + rr;   // this lane's batch row
  const int kb8  = q << 3;

  // ---- prologue: prefetch x(0) into Xl[0] (drained by poll(0)'s vmcnt) ----
  if constexpr (USE_XB) {
    const short* xr0 = xb + (size_t)rowb * S_ * D_;
#pragma unroll
    for (int ks = 0; ks < 16; ++ks)
      gload_lds16(xr0 + ks * 32 + kb8, &Xl[0][ks * 512]);
  }

  __syncthreads();                   // Wl ready (single wave; effectively free)

  float cst[4] = {0.f, 0.f, 0.f, 0.f};   // cell state: 4 cols of row rowb

  for (int t = 0; t < S_; ++t) {
    const char* hrd = hbc + (t & 1) * (B_ * NCS * 16);
    char*       hwr = hbc + ((t + 1) & 1) * (B_ * NCS * 16);

    f32x4 acc0 = {0.f, 0.f, 0.f, 0.f};   // gatecols [0,16):  f | i
    f32x4 acc1 = {0.f, 0.f, 0.f, 0.f};   // gatecols [16,32): g | o
    U128 rc0, rc1, rc2, rc3, rc4, rc5, rc6, rc7,
         rc8, rc9, rc10, rc11, rc12, rc13, rc14, rc15;

    // Poll tagged fragment records (detection == data load). Lane needs
    // records (rowb, cs = 4*ks + q): base rowb*1024 + q*16, stride 64B, 16
    // loads; 4 q-groups share 64B lines per instruction. Each attempt's
    // vmcnt(0) also drains: previous-step record stores (parity-reuse
    // induction) AND the in-flight x-prefetch for THIS step's x-part.
#define POLL_RECORDS()                                                         \
    {                                                                          \
      const char* rb = hrd + (rowb << 10) + (q << 4);                          \
      const unsigned int t0 = (unsigned int)t;                                 \
      const unsigned int t1 = (unsigned int)t >> 1;                            \
      while (true) {                                                           \
        asm volatile(                                                          \
          "global_load_dwordx4 %[r0], %[p], off sc1\n\t"                       \
          "global_load_dwordx4 %[r1], %[p], off offset:64 sc1\n\t"             \
          "global_load_dwordx4 %[r2], %[p], off offset:128 sc1\n\t"            \
          "global_load_dwordx4 %[r3], %[p], off offset:192 sc1\n\t"            \
          "global_load_dwordx4 %[r4], %[p], off offset:256 sc1\n\t"            \
          "global_load_dwordx4 %[r5], %[p], off offset:320 sc1\n\t"            \
          "global_load_dwordx4 %[r6], %[p], off offset:384 sc1\n\t"            \
          "global_load_dwordx4 %[r7], %[p], off offset:448 sc1\n\t"            \
          "global_load_dwordx4 %[r8], %[p], off offset:512 sc1\n\t"            \
          "global_load_dwordx4 %[r9], %[p], off offset:576 sc1\n\t"            \
          "global_load_dwordx4 %[r10], %[p], off offset:640 sc1\n\t"           \
          "global_load_dwordx4 %[r11], %[p], off offset:704 sc1\n\t"           \
          "global_load_dwordx4 %[r12], %[p], off offset:768 sc1\n\t"           \
          "global_load_dwordx4 %[r13], %[p], off offset:832 sc1\n\t"           \
          "global_load_dwordx4 %[r14], %[p], off offset:896 sc1\n\t"           \
          "global_load_dwordx4 %[r15], %[p], off offset:960 sc1\n\t"           \
          "s_waitcnt vmcnt(0)"                                                 \
          : [r0]"=&v"(rc0.s), [r1]"=&v"(rc1.s), [r2]"=&v"(rc2.s),              \
            [r3]"=&v"(rc3.s), [r4]"=&v"(rc4.s), [r5]"=&v"(rc5.s),              \
            [r6]"=&v"(rc6.s), [r7]"=&v"(rc7.s), [r8]"=&v"(rc8.s),              \
            [r9]"=&v"(rc9.s), [r10]"=&v"(rc10.s), [r11]"=&v"(rc11.s),          \
            [r12]"=&v"(rc12.s), [r13]"=&v"(rc13.s), [r14]"=&v"(rc14.s),        \
            [r15]"=&v"(rc15.s)                                                 \
          : [p]"v"(rb)                                                         \
          : "memory");                                                         \
        const unsigned int bad =                                               \
            TCHK(rc0)  | TCHK(rc1)  | TCHK(rc2)  | TCHK(rc3)  |                \
            TCHK(rc4)  | TCHK(rc5)  | TCHK(rc6)  | TCHK(rc7)  |                \
            TCHK(rc8)  | TCHK(rc9)  | TCHK(rc10) | TCHK(rc11) |                \
            TCHK(rc12) | TCHK(rc13) | TCHK(rc14) | TCHK(rc15);                 \
        if (__all((int)(bad == 0u))) break;                                    \
      }                                                                        \
    }
#define TCHK(R) ( ((R.w[0] ^ t0) & 1u) | ((R.w[2] ^ t1) & 1u) )

    if constexpr (USE_XB) {
      // ---- poll FIRST: its vmcnt(0) drains the x(t) prefetch issued last
      //      iteration, so the LDS x-buffer is ready the moment we pass. ----
      POLL_RECORDS();

      // ---- issue x(t+1) prefetch immediately (flies under MFMAs + next
      //      poll-spin; drained by poll(t+1)) ----
      if (t < S_ - 1) {
        const short* xr1 = xb + (size_t)rowb * S_ * D_ + (size_t)(t + 1) * D_;
#pragma unroll
        for (int ks = 0; ks < 16; ++ks)
          gload_lds16(xr1 + ks * 32 + kb8, &Xl[(t + 1) & 1][ks * 512]);
      }

      // ---- x-part from LDS (fast ds_read_b128; HBM latency now off-chain) ----
      const short* xl = &Xl[t & 1][lane << 3];
#pragma unroll 4
      for (int ks = 0; ks < 16; ++ks) {
        short8 a = *(const short8*)(xl + ks * 512);
        const int kw = 512 + ks * 32 + kb8;
        short8 b0 = *(const short8*)((const char*)Wl + wl_byte(lane & 15, kw));
        short8 b1 = *(const short8*)((const char*)Wl + wl_byte(16 + (lane & 15), kw));
        acc0 = __builtin_amdgcn_mfma_f32_16x16x32_bf16(b0, a, acc0, 0, 0, 0);
        acc1 = __builtin_amdgcn_mfma_f32_16x16x32_bf16(b1, a, acc1, 0, 0, 0);
      }
    } else {
      // Fallback (no workspace): R11 order — x inline f32, then poll.
      const float* xr = xg + (size_t)rowb * S_ * D_ + (size_t)t * D_;
#pragma unroll 4
      for (int ks = 0; ks < 16; ++ks) {
        const int kx = ks * 32 + kb8;
        f32x4 f0 = *(const f32x4*)(xr + kx);
        f32x4 f1 = *(const f32x4*)(xr + kx + 4);
        short8 a;
#pragma unroll
        for (int j = 0; j < 4; ++j) { a[j] = f2bf(f0[j]); a[4 + j] = f2bf(f1[j]); }
        const int kw = 512 + kx;
        short8 b0 = *(const short8*)((const char*)Wl + wl_byte(lane & 15, kw));
        short8 b1 = *(const short8*)((const char*)Wl + wl_byte(16 + (lane & 15), kw));
        acc0 = __builtin_amdgcn_mfma_f32_16x16x32_bf16(b0, a, acc0, 0, 0, 0);
        acc1 = __builtin_amdgcn_mfma_f32_16x16x32_bf16(b1, a, acc1, 0, 0, 0);
      }
      POLL_RECORDS();
    }
#undef TCHK
#undef POLL_RECORDS

    // ---- h-part: two independent 8-deep MFMA chains per acc ----
    {
      f32x4 acc0b = {0.f, 0.f, 0.f, 0.f};
      f32x4 acc1b = {0.f, 0.f, 0.f, 0.f};
#define HSTEP(KS, RA, A0, A1)                                                  \
      {                                                                        \
        const int k0_ = (KS) * 32 + kb8;                                       \
        short8 b0_ = *(const short8*)((const char*)Wl + wl_byte(lane & 15, k0_)); \
        short8 b1_ = *(const short8*)((const char*)Wl + wl_byte(16 + (lane & 15), k0_)); \
        A0 = __builtin_amdgcn_mfma_f32_16x16x32_bf16(b0_, RA.s, A0, 0, 0, 0);  \
        A1 = __builtin_amdgcn_mfma_f32_16x16x32_bf16(b1_, RA.s, A1, 0, 0, 0);  \
      }
      HSTEP(0,  rc0,  acc0,  acc1)  HSTEP(1,  rc1,  acc0b, acc1b)
      HSTEP(2,  rc2,  acc0,  acc1)  HSTEP(3,  rc3,  acc0b, acc1b)
      HSTEP(4,  rc4,  acc0,  acc1)  HSTEP(5,  rc5,  acc0b, acc1b)
      HSTEP(6,  rc6,  acc0,  acc1)  HSTEP(7,  rc7,  acc0b, acc1b)
      HSTEP(8,  rc8,  acc0,  acc1)  HSTEP(9,  rc9,  acc0b, acc1b)
      HSTEP(10, rc10, acc0,  acc1)  HSTEP(11, rc11, acc0b, acc1b)
      HSTEP(12, rc12, acc0,  acc1)  HSTEP(13, rc13, acc0b, acc1b)
      HSTEP(14, rc14, acc0,  acc1)  HSTEP(15, rc15, acc0b, acc1b)
#undef HSTEP
#pragma unroll
      for (int j = 0; j < 4; ++j) { acc0[j] += acc0b[j]; acc1[j] += acc1b[j]; }
    }

    // ---- epilogue: exchange f<->i / g<->o halves across lane^32 ----
    f32x4 x0, x1;
#pragma unroll
    for (int j = 0; j < 4; ++j) {
      x0[j] = __shfl_xor(acc0[j], 32);
      x1[j] = __shfl_xor(acc1[j], 32);
    }
    const bool lo = (q < 2);
    float hv[4];
#pragma unroll
    for (int r = 0; r < 4; ++r) {
      const float sF = (lo ? acc0[r] : x0[r]) + bF4[r];
      const float sI = (lo ? x0[r] : acc0[r]) + bI4[r];
      const float sG = (lo ? acc1[r] : x1[r]) + bG4[r];
      const float sO = (lo ? x1[r] : acc1[r]) + bO4[r];
      const float fg = sigm(sF);
      const float ig = sigm(sI);
      const float gg = tanh_(sG);
      const float og = sigm(sO);
      const float cn = cst[r] * fg + gg * ig;
      cst[r] = cn;
      hv[r] = og * tanh_(cn);
    }

    // ---- record broadcast: merge the two col-quads of this cs across
    //      lane^16, embed tag bits, ONE 16B store per row (q==0 lanes) ----
    unsigned long long hp8;
    {
      unsigned int l32 = (unsigned int)(unsigned short)f2bf(hv[0])
                       | ((unsigned int)(unsigned short)f2bf(hv[1]) << 16);
      unsigned int h32 = (unsigned int)(unsigned short)f2bf(hv[2])
                       | ((unsigned int)(unsigned short)f2bf(hv[3]) << 16);
      hp8 = (unsigned long long)l32 | ((unsigned long long)h32 << 32);
    }
    unsigned long long other = __shfl_xor(hp8, 16);  // partner quad, same row
    if (q == 0 && t < S_ - 1) {
      const unsigned int tag = (unsigned int)(t + 1);
      U128 u;
      u.w[0] = ((unsigned int)hp8 & ~1u) | (tag & 1u);          // col0 LSB=bit0
      u.w[1] = (unsigned int)(hp8 >> 32);
      u.w[2] = ((unsigned int)other & ~1u) | ((tag >> 1) & 1u); // col4 LSB=bit1
      u.w[3] = (unsigned int)(other >> 32);
      store_b128_dev(hwr + (rowb << 10) + (cs << 4), u.s);
    }

    if (lo) {
      // ---- out: one 16B store per lane, full-precision f32 ----
      f32x4 hv4;
#pragma unroll
      for (int r = 0; r < 4; ++r) hv4[r] = hv[r];
      *(f32x4*)(out + (size_t)rowb * ((size_t)S_ * H_) + (size_t)t * H_ + colq) = hv4;
      if (t == S_ - 1) {
        f32x4 c4;
#pragma unroll
        for (int r = 0; r < 4; ++r) c4[r] = cst[r];
        *(f32x4*)(out + (size_t)B_ * S_ * H_ + (size_t)rowb * H_ + colq) = hv4;
        *(f32x4*)(out + (size_t)B_ * S_ * H_ + (size_t)B_ * H_
                      + (size_t)rowb * H_ + colq) = c4;
      }
    }
    // No drain, no flag, no barrier: tags ride with the data.
  }
}

extern "C" void kernel_launch(void* const* d_in, const int* in_sizes, int n_in,
                              void* d_out, int out_size, void* d_ws, size_t ws_size,
                              hipStream_t stream) {
  (void)in_sizes; (void)n_in; (void)out_size;
  const float* x  = (const float*)d_in[0];
  const float* Wf = (const float*)d_in[1];
  const float* bf = (const float*)d_in[2];
  const float* Wi = (const float*)d_in[3];
  const float* bi = (const float*)d_in[4];
  const float* Wc = (const float*)d_in[5];
  const float* bc = (const float*)d_in[6];
  const float* Wo = (const float*)d_in[7];
  const float* bo = (const float*)d_in[8];
  float* out = (float*)d_out;

  char* hbc = (char*)d_ws;   // 128 KB: [2][64][64][16B] tagged fragment records

  const size_t XB_OFF   = (size_t)1 << 20;                        // 1 MB
  const size_t XB_BYTES = (size_t)B_ * S_ * D_ * sizeof(short);   // 64 MB

  // zero both parities: tag bits 0 == t=0 mod 4, data 0 == h_0; captured in
  // the graph, so every replay starts from a clean state.
  hipMemsetAsync(d_ws, 0, 2 * B_ * NCS * 16, stream);

  if (ws_size >= XB_OFF + XB_BYTES) {
    short* xb = (short*)((char*)d_ws + XB_OFF);
    lstm_xprep<<<dim3((B_ * S_ * D_) / (256 * 8)), dim3(256), 0, stream>>>(x, xb);
    lstm_persist<1><<<dim3(NWG), dim3(NT), 0, stream>>>(
        x, xb, Wf, bf, Wi, bi, Wc, bc, Wo, bo, out, hbc);
  } else {
    lstm_persist<0><<<dim3(NWG), dim3(NT), 0, stream>>>(
        x, nullptr, Wf, bf, Wi, bi, Wc, bc, Wo, bo, out, hbc);
  }
}

// Round 15
// 5657.039 us; speedup vs baseline: 1.0463x; 1.0463x over previous
//
#include <hip/hip_runtime.h>
#include <hip/hip_bf16.h>

#define B_   64
#define S_   1024
#define D_   512
#define H_   512
#define NWG  256    // 1 wave per WG -> 1 per CU; 4 row-cohorts x 64 col-slices
#define NCS  64     // column slices
#define HCW  8      // h-columns per col-slice
#define NT   64

typedef __attribute__((ext_vector_type(8))) short short8;
typedef __attribute__((ext_vector_type(4))) float f32x4;

// Swizzled byte offset into the LDS W tile: [gc][k] bf16, row = 2048 B.
__device__ __forceinline__ int wl_byte(int gc, int k) {
  return ((gc << 11) + (k << 1)) ^ ((gc & 7) << 4);
}
__device__ __forceinline__ float sigm(float v) { return 1.0f / (1.0f + __expf(-v)); }
__device__ __forceinline__ float tanh_(float v) { return 1.0f - 2.0f / (__expf(2.0f * v) + 1.0f); }
__device__ __forceinline__ short f2bf(float f) {
  __hip_bfloat16 h = __float2bfloat16(f);
  short s;
  __builtin_memcpy(&s, &h, 2);
  return s;
}

union U128 { unsigned long long u[2]; unsigned int w[4]; short8 s; };

// DEVICE-scope (sc1) 16B store: bypasses the XCD-private L2 (the non-coherent
// boundary), resolves at the on-die LLC. Single transaction -> record atomic
// (MUST stay one dwordx4: tag bit1 lives in col4).
__device__ __forceinline__ void store_b128_dev(void* p, short8 v) {
  asm volatile("global_store_dwordx4 %0, %1, off sc1" :: "v"(p), "v"(v) : "memory");
}

// ---------------------------------------------------------------------------
// Prep: xb = bf16(x), same [B][S][D] layout.
// ---------------------------------------------------------------------------
__global__ __launch_bounds__(256, 1) void lstm_xprep(
    const float* __restrict__ xg, short* __restrict__ xb)
{
  const size_t i = ((size_t)blockIdx.x * 256 + threadIdx.x) * 8;
  f32x4 a = *(const f32x4*)(xg + i);
  f32x4 b = *(const f32x4*)(xg + i + 4);
  short8 v;
#pragma unroll
  for (int j = 0; j < 4; ++j) { v[j] = f2bf(a[j]); v[4 + j] = f2bf(b[j]); }
  *(short8*)(xb + i) = v;
}

// Record format (16B, one per (row, cs)): 8 bf16 = one MFMA A-fragment.
// Step tag (t mod 4) embedded as LSBs of col0 (bit0) and col4 (bit1).
// Poll-passing induction bounds slot staleness to {t, t-2}; bit1 separates.

template<int USE_XB>
__global__ __launch_bounds__(NT, 1) void lstm_persist(
    const float* __restrict__ xg, const short* __restrict__ xb,
    const float* __restrict__ Wf, const float* __restrict__ bfv,
    const float* __restrict__ Wi, const float* __restrict__ biv,
    const float* __restrict__ Wc, const float* __restrict__ bcv,
    const float* __restrict__ Wo, const float* __restrict__ bov,
    float* __restrict__ out,
    char* __restrict__ hbc)   // [2][64 rows][64 cs][16B] tagged fragment records
{
  __shared__ short Wl[32 * 1024];    // 64 KB: W slice, [gc][k] bf16, swizzled

  const int tid  = threadIdx.x;
  const int wg   = blockIdx.x;
  const int cs   = wg >> 2;          // column slice 0..63
  const int rc   = wg & 3;           // row cohort 0..3 (16 batch rows)
  const int lane = tid;              // single wave

  // ---- one-time: stage this WG's W slice (transposed to [gc][k], bf16) ----
  {
    const float* Wg4[4] = {Wf, Wi, Wc, Wo};
    const int gc  = tid >> 1;        // 0..31
    const int seg = tid & 1;         // k half of 512
    const float* Wsrc = Wg4[gc >> 3];
    const int col = cs * HCW + (gc & 7);
    for (int kk = 0; kk < 512; ++kk) {
      const int k = seg * 512 + kk;
      *(short*)((char*)Wl + wl_byte(gc, k)) = f2bf(Wsrc[(size_t)k * H_ + col]);
    }
  }

  // Transposed-C lane mapping: lane&15 = batch row, (lane>>4)*4+reg = gatecol.
  const int q    = lane >> 4;        // 0..3
  const int rr   = lane & 15;        // batch row within wave tile
  const int c0   = (q & 1) << 2;     // col-quad base within slice's 8 cols
  const int colq = cs * HCW + c0;    // global col-quad base
  float bF4[4], bI4[4], bG4[4], bO4[4];
#pragma unroll
  for (int r = 0; r < 4; ++r) {
    bF4[r] = bfv[colq + r]; bI4[r] = biv[colq + r];
    bG4[r] = bcv[colq + r]; bO4[r] = bov[colq + r];
  }

  __syncthreads();                   // Wl ready (single wave; effectively free)

  const int rowb = (rc << 4) + rr;   // this lane's batch row
  const int kb8  = q << 3;

  float cst[4] = {0.f, 0.f, 0.f, 0.f};   // cell state: 4 cols of row rowb

#define LSTM_TCHK(R) ( ((R.w[0] ^ t0_) & 1u) | ((R.w[2] ^ t1_) & 1u) )
#define LSTM_POLL(HRD)                                                         \
      {                                                                        \
        const char* rb_ = (HRD) + (rowb << 10) + (q << 4);                     \
        while (true) {                                                         \
          asm volatile(                                                        \
            "global_load_dwordx4 %[r0], %[p], off sc1\n\t"                     \
            "global_load_dwordx4 %[r1], %[p], off offset:64 sc1\n\t"           \
            "global_load_dwordx4 %[r2], %[p], off offset:128 sc1\n\t"          \
            "global_load_dwordx4 %[r3], %[p], off offset:192 sc1\n\t"          \
            "global_load_dwordx4 %[r4], %[p], off offset:256 sc1\n\t"          \
            "global_load_dwordx4 %[r5], %[p], off offset:320 sc1\n\t"          \
            "global_load_dwordx4 %[r6], %[p], off offset:384 sc1\n\t"          \
            "global_load_dwordx4 %[r7], %[p], off offset:448 sc1\n\t"          \
            "global_load_dwordx4 %[r8], %[p], off offset:512 sc1\n\t"          \
            "global_load_dwordx4 %[r9], %[p], off offset:576 sc1\n\t"          \
            "global_load_dwordx4 %[r10], %[p], off offset:640 sc1\n\t"         \
            "global_load_dwordx4 %[r11], %[p], off offset:704 sc1\n\t"         \
            "global_load_dwordx4 %[r12], %[p], off offset:768 sc1\n\t"         \
            "global_load_dwordx4 %[r13], %[p], off offset:832 sc1\n\t"         \
            "global_load_dwordx4 %[r14], %[p], off offset:896 sc1\n\t"         \
            "global_load_dwordx4 %[r15], %[p], off offset:960 sc1\n\t"         \
            "s_waitcnt vmcnt(0)"                                               \
            : [r0]"=&v"(rc0.s), [r1]"=&v"(rc1.s), [r2]"=&v"(rc2.s),            \
              [r3]"=&v"(rc3.s), [r4]"=&v"(rc4.s), [r5]"=&v"(rc5.s),            \
              [r6]"=&v"(rc6.s), [r7]"=&v"(rc7.s), [r8]"=&v"(rc8.s),            \
              [r9]"=&v"(rc9.s), [r10]"=&v"(rc10.s), [r11]"=&v"(rc11.s),        \
              [r12]"=&v"(rc12.s), [r13]"=&v"(rc13.s), [r14]"=&v"(rc14.s),      \
              [r15]"=&v"(rc15.s)                                               \
            : [p]"v"(rb_)                                                      \
            : "memory");                                                       \
          const unsigned int bad_ =                                            \
              LSTM_TCHK(rc0)  | LSTM_TCHK(rc1)  | LSTM_TCHK(rc2)  |            \
              LSTM_TCHK(rc3)  | LSTM_TCHK(rc4)  | LSTM_TCHK(rc5)  |            \
              LSTM_TCHK(rc6)  | LSTM_TCHK(rc7)  | LSTM_TCHK(rc8)  |            \
              LSTM_TCHK(rc9)  | LSTM_TCHK(rc10) | LSTM_TCHK(rc11) |            \
              LSTM_TCHK(rc12) | LSTM_TCHK(rc13) | LSTM_TCHK(rc14) |            \
              LSTM_TCHK(rc15);                                                 \
          if (__all((int)(bad_ == 0u))) break;                                 \
        }                                                                      \
      }

#define LSTM_EPILOGUE()                                                        \
      f32x4 e0, e1;                                                            \
      _Pragma("unroll")                                                        \
      for (int j = 0; j < 4; ++j) {                                            \
        e0[j] = __shfl_xor(acc0[j], 32);                                       \
        e1[j] = __shfl_xor(acc1[j], 32);                                       \
      }                                                                        \
      const bool lo = (q < 2);                                                 \
      float hv[4];                                                             \
      _Pragma("unroll")                                                        \
      for (int r = 0; r < 4; ++r) {                                            \
        const float sF = (lo ? acc0[r] : e0[r]) + bF4[r];                      \
        const float sI = (lo ? e0[r] : acc0[r]) + bI4[r];                      \
        const float sG = (lo ? acc1[r] : e1[r]) + bG4[r];                      \
        const float sO = (lo ? e1[r] : acc1[r]) + bO4[r];                      \
        const float fg = sigm(sF);                                             \
        const float ig = sigm(sI);                                             \
        const float gg = tanh_(sG);                                            \
        const float og = sigm(sO);                                             \
        const float cn = cst[r] * fg + gg * ig;                                \
        cst[r] = cn;                                                           \
        hv[r] = og * tanh_(cn);                                                \
      }                                                                        \
      unsigned long long hp8;                                                  \
      {                                                                        \
        unsigned int l32 = (unsigned int)(unsigned short)f2bf(hv[0])           \
                         | ((unsigned int)(unsigned short)f2bf(hv[1]) << 16);  \
        unsigned int h32 = (unsigned int)(unsigned short)f2bf(hv[2])           \
                         | ((unsigned int)(unsigned short)f2bf(hv[3]) << 16);  \
        hp8 = (unsigned long long)l32 | ((unsigned long long)h32 << 32);       \
      }                                                                        \
      unsigned long long other = __shfl_xor(hp8, 16);                          \
      if (q == 0 && t_ < S_ - 1) {                                             \
        const unsigned int tag = (unsigned int)(t_ + 1);                       \
        U128 u;                                                                \
        u.w[0] = ((unsigned int)hp8 & ~1u) | (tag & 1u);                       \
        u.w[1] = (unsigned int)(hp8 >> 32);                                    \
        u.w[2] = ((unsigned int)other & ~1u) | ((tag >> 1) & 1u);              \
        u.w[3] = (unsigned int)(other >> 32);                                  \
        store_b128_dev(hwr_ + (rowb << 10) + (cs << 4), u.s);                  \
      }                                                                        \
      if (lo) {                                                                \
        f32x4 hv4;                                                             \
        _Pragma("unroll")                                                      \
        for (int r = 0; r < 4; ++r) hv4[r] = hv[r];                            \
        *(f32x4*)(out + (size_t)rowb * ((size_t)S_ * H_) + (size_t)t_ * H_ + colq) = hv4; \
        if (t_ == S_ - 1) {                                                    \
          f32x4 c4;                                                            \
          _Pragma("unroll")                                                    \
          for (int r = 0; r < 4; ++r) c4[r] = cst[r];                          \
          *(f32x4*)(out + (size_t)B_ * S_ * H_ + (size_t)rowb * H_ + colq) = hv4; \
          *(f32x4*)(out + (size_t)B_ * S_ * H_ + (size_t)B_ * H_               \
                        + (size_t)rowb * H_ + colq) = c4;                      \
        }                                                                      \
      }

  if constexpr (USE_XB) {
    const short* xrow = xb + (size_t)rowb * S_ * D_;
    short8 xA[16], xB[16];
    // prologue: x(0) -> xA (drained by poll(0)'s vmcnt)
#pragma unroll
    for (int ks = 0; ks < 16; ++ks)
      xA[ks] = *(const short8*)(xrow + ks * 32 + kb8);

    // Per iteration t: poll(t) [drains x(t) regs loaded last iter] ->
    // x-MFMA(XC) + h-MFMA(records), independent chains -> sched_barrier ->
    // issue x(t+1) loads into XN (fly under epilogue/stores/next poll) ->
    // merge chains -> epilogue/publish. x HBM latency is now off the serial
    // cycle; in-cycle x cost = 32 MFMA issues.
#define LSTM_BODY(T, XC, XN)                                                   \
    {                                                                          \
      const int t_ = (T);                                                      \
      const char* hrd_ = hbc + (t_ & 1) * (B_ * NCS * 16);                     \
      char*       hwr_ = hbc + ((t_ + 1) & 1) * (B_ * NCS * 16);               \
      const unsigned int t0_ = (unsigned int)t_;                               \
      const unsigned int t1_ = (unsigned int)t_ >> 1;                          \
      U128 rc0, rc1, rc2, rc3, rc4, rc5, rc6, rc7,                             \
           rc8, rc9, rc10, rc11, rc12, rc13, rc14, rc15;                       \
      LSTM_POLL(hrd_);                                                         \
      f32x4 aX0 = {0.f,0.f,0.f,0.f}, aX1 = {0.f,0.f,0.f,0.f};                  \
      _Pragma("unroll")                                                        \
      for (int ks = 0; ks < 16; ++ks) {                                        \
        const int kw_ = 512 + ks * 32 + kb8;                                   \
        short8 b0_ = *(const short8*)((const char*)Wl + wl_byte(lane & 15, kw_)); \
        short8 b1_ = *(const short8*)((const char*)Wl + wl_byte(16 + (lane & 15), kw_)); \
        aX0 = __builtin_amdgcn_mfma_f32_16x16x32_bf16(b0_, XC[ks], aX0, 0, 0, 0); \
        aX1 = __builtin_amdgcn_mfma_f32_16x16x32_bf16(b1_, XC[ks], aX1, 0, 0, 0); \
      }                                                                        \
      f32x4 aHa0 = {0.f,0.f,0.f,0.f}, aHb0 = {0.f,0.f,0.f,0.f};                \
      f32x4 aHa1 = {0.f,0.f,0.f,0.f}, aHb1 = {0.f,0.f,0.f,0.f};                \
      HS_(0,  rc0,  aHa0, aHa1)  HS_(1,  rc1,  aHb0, aHb1)                     \
      HS_(2,  rc2,  aHa0, aHa1)  HS_(3,  rc3,  aHb0, aHb1)                     \
      HS_(4,  rc4,  aHa0, aHa1)  HS_(5,  rc5,  aHb0, aHb1)                     \
      HS_(6,  rc6,  aHa0, aHa1)  HS_(7,  rc7,  aHb0, aHb1)                     \
      HS_(8,  rc8,  aHa0, aHa1)  HS_(9,  rc9,  aHb0, aHb1)                     \
      HS_(10, rc10, aHa0, aHa1)  HS_(11, rc11, aHb0, aHb1)                     \
      HS_(12, rc12, aHa0, aHa1)  HS_(13, rc13, aHb0, aHb1)                     \
      HS_(14, rc14, aHa0, aHa1)  HS_(15, rc15, aHb0, aHb1)                     \
      __builtin_amdgcn_sched_barrier(0);                                       \
      if (t_ < S_ - 1) {                                                       \
        const short* xrn_ = xrow + (size_t)(t_ + 1) * D_;                      \
        _Pragma("unroll")                                                      \
        for (int ks = 0; ks < 16; ++ks)                                        \
          XN[ks] = *(const short8*)(xrn_ + ks * 32 + kb8);                     \
      }                                                                        \
      f32x4 acc0, acc1;                                                        \
      _Pragma("unroll")                                                        \
      for (int j = 0; j < 4; ++j) {                                            \
        acc0[j] = aX0[j] + aHa0[j] + aHb0[j];                                  \
        acc1[j] = aX1[j] + aHa1[j] + aHb1[j];                                  \
      }                                                                        \
      LSTM_EPILOGUE();                                                         \
    }
#define HS_(KS, RA, A0, A1)                                                    \
      {                                                                        \
        const int k0_ = (KS) * 32 + kb8;                                       \
        short8 b0_ = *(const short8*)((const char*)Wl + wl_byte(lane & 15, k0_)); \
        short8 b1_ = *(const short8*)((const char*)Wl + wl_byte(16 + (lane & 15), k0_)); \
        A0 = __builtin_amdgcn_mfma_f32_16x16x32_bf16(b0_, RA.s, A0, 0, 0, 0);  \
        A1 = __builtin_amdgcn_mfma_f32_16x16x32_bf16(b1_, RA.s, A1, 0, 0, 0);  \
      }

    for (int tt = 0; tt < S_; tt += 2) {
      LSTM_BODY(tt, xA, xB)
      LSTM_BODY(tt + 1, xB, xA)
    }
#undef HS_
#undef LSTM_BODY
  } else {
    // Fallback (no workspace): R11 structure — x inline f32 before the poll.
    for (int t = 0; t < S_; ++t) {
      const int t_ = t;
      const char* hrd_ = hbc + (t_ & 1) * (B_ * NCS * 16);
      char*       hwr_ = hbc + ((t_ + 1) & 1) * (B_ * NCS * 16);
      const unsigned int t0_ = (unsigned int)t_;
      const unsigned int t1_ = (unsigned int)t_ >> 1;

      f32x4 acc0 = {0.f, 0.f, 0.f, 0.f};
      f32x4 acc1 = {0.f, 0.f, 0.f, 0.f};
      const float* xr = xg + (size_t)rowb * S_ * D_ + (size_t)t_ * D_;
#pragma unroll 4
      for (int ks = 0; ks < 16; ++ks) {
        const int kx = ks * 32 + kb8;
        f32x4 f0 = *(const f32x4*)(xr + kx);
        f32x4 f1 = *(const f32x4*)(xr + kx + 4);
        short8 a;
#pragma unroll
        for (int j = 0; j < 4; ++j) { a[j] = f2bf(f0[j]); a[4 + j] = f2bf(f1[j]); }
        const int kw = 512 + kx;
        short8 b0 = *(const short8*)((const char*)Wl + wl_byte(lane & 15, kw));
        short8 b1 = *(const short8*)((const char*)Wl + wl_byte(16 + (lane & 15), kw));
        acc0 = __builtin_amdgcn_mfma_f32_16x16x32_bf16(b0, a, acc0, 0, 0, 0);
        acc1 = __builtin_amdgcn_mfma_f32_16x16x32_bf16(b1, a, acc1, 0, 0, 0);
      }

      U128 rc0, rc1, rc2, rc3, rc4, rc5, rc6, rc7,
           rc8, rc9, rc10, rc11, rc12, rc13, rc14, rc15;
      LSTM_POLL(hrd_);

      f32x4 acc0b = {0.f, 0.f, 0.f, 0.f};
      f32x4 acc1b = {0.f, 0.f, 0.f, 0.f};
#define HS_(KS, RA, A0, A1)                                                    \
      {                                                                        \
        const int k0_ = (KS) * 32 + kb8;                                       \
        short8 b0_ = *(const short8*)((const char*)Wl + wl_byte(lane & 15, k0_)); \
        short8 b1_ = *(const short8*)((const char*)Wl + wl_byte(16 + (lane & 15), k0_)); \
        A0 = __builtin_amdgcn_mfma_f32_16x16x32_bf16(b0_, RA.s, A0, 0, 0, 0);  \
        A1 = __builtin_amdgcn_mfma_f32_16x16x32_bf16(b1_, RA.s, A1, 0, 0, 0);  \
      }
      HS_(0,  rc0,  acc0,  acc1)  HS_(1,  rc1,  acc0b, acc1b)
      HS_(2,  rc2,  acc0,  acc1)  HS_(3,  rc3,  acc0b, acc1b)
      HS_(4,  rc4,  acc0,  acc1)  HS_(5,  rc5,  acc0b, acc1b)
      HS_(6,  rc6,  acc0,  acc1)  HS_(7,  rc7,  acc0b, acc1b)
      HS_(8,  rc8,  acc0,  acc1)  HS_(9,  rc9,  acc0b, acc1b)
      HS_(10, rc10, acc0,  acc1)  HS_(11, rc11, acc0b, acc1b)
      HS_(12, rc12, acc0,  acc1)  HS_(13, rc13, acc0b, acc1b)
      HS_(14, rc14, acc0,  acc1)  HS_(15, rc15, acc0b, acc1b)
#undef HS_
#pragma unroll
      for (int j = 0; j < 4; ++j) { acc0[j] += acc0b[j]; acc1[j] += acc1b[j]; }

      LSTM_EPILOGUE();
    }
  }
#undef LSTM_EPILOGUE
#undef LSTM_POLL
#undef LSTM_TCHK
}

extern "C" void kernel_launch(void* const* d_in, const int* in_sizes, int n_in,
                              void* d_out, int out_size, void* d_ws, size_t ws_size,
                              hipStream_t stream) {
  (void)in_sizes; (void)n_in; (void)out_size;
  const float* x  = (const float*)d_in[0];
  const float* Wf = (const float*)d_in[1];
  const float* bf = (const float*)d_in[2];
  const float* Wi = (const float*)d_in[3];
  const float* bi = (const float*)d_in[4];
  const float* Wc = (const float*)d_in[5];
  const float* bc = (const float*)d_in[6];
  const float* Wo = (const float*)d_in[7];
  const float* bo = (const float*)d_in[8];
  float* out = (float*)d_out;

  char* hbc = (char*)d_ws;   // 128 KB: [2][64][64][16B] tagged fragment records

  const size_t XB_OFF   = (size_t)1 << 20;                        // 1 MB
  const size_t XB_BYTES = (size_t)B_ * S_ * D_ * sizeof(short);   // 64 MB

  // zero both parities: tag bits 0 == t=0 mod 4, data 0 == h_0; captured in
  // the graph, so every replay starts from a clean state.
  hipMemsetAsync(d_ws, 0, 2 * B_ * NCS * 16, stream);

  if (ws_size >= XB_OFF + XB_BYTES) {
    short* xb = (short*)((char*)d_ws + XB_OFF);
    lstm_xprep<<<dim3((B_ * S_ * D_) / (256 * 8)), dim3(256), 0, stream>>>(x, xb);
    lstm_persist<1><<<dim3(NWG), dim3(NT), 0, stream>>>(
        x, xb, Wf, bf, Wi, bi, Wc, bc, Wo, bo, out, hbc);
  } else {
    lstm_persist<0><<<dim3(NWG), dim3(NT), 0, stream>>>(
        x, nullptr, Wf, bf, Wi, bi, Wc, bc, Wo, bo, out, hbc);
  }
}

// Round 16
// 4247.906 us; speedup vs baseline: 1.3934x; 1.3317x over previous
//
#include <hip/hip_runtime.h>
#include <hip/hip_bf16.h>

#define B_   64
#define S_   1024
#define D_   512
#define H_   512
#define NWG  256    // 1 wave per WG -> 1 per CU; 4 row-cohorts x 64 col-slices
#define NCS  64     // column slices
#define HCW  8      // h-columns per col-slice
#define NT   64

typedef __attribute__((ext_vector_type(8))) short short8;
typedef __attribute__((ext_vector_type(4))) float f32x4;

// Swizzled byte offset into the LDS W tile: [gc][k] bf16, row = 2048 B.
__device__ __forceinline__ int wl_byte(int gc, int k) {
  return ((gc << 11) + (k << 1)) ^ ((gc & 7) << 4);
}
__device__ __forceinline__ float sigm(float v) { return 1.0f / (1.0f + __expf(-v)); }
__device__ __forceinline__ float tanh_(float v) { return 1.0f - 2.0f / (__expf(2.0f * v) + 1.0f); }
__device__ __forceinline__ short f2bf(float f) {
  __hip_bfloat16 h = __float2bfloat16(f);
  short s;
  __builtin_memcpy(&s, &h, 2);
  return s;
}

union U128 { unsigned long long u[2]; unsigned int w[4]; short8 s; };

// DEVICE-scope (sc1) 16B store: bypasses the XCD-private L2 (the non-coherent
// boundary), resolves at the on-die LLC. Single transaction -> record atomic
// (MUST stay one dwordx4: tag bit1 lives in col4).
__device__ __forceinline__ void store_b128_dev(void* p, short8 v) {
  asm volatile("global_store_dwordx4 %0, %1, off sc1" :: "v"(p), "v"(v) : "memory");
}

// ---------------------------------------------------------------------------
// Prep: xb = bf16(x), same [B][S][D] layout.
// ---------------------------------------------------------------------------
__global__ __launch_bounds__(256, 1) void lstm_xprep(
    const float* __restrict__ xg, short* __restrict__ xb)
{
  const size_t i = ((size_t)blockIdx.x * 256 + threadIdx.x) * 8;
  f32x4 a = *(const f32x4*)(xg + i);
  f32x4 b = *(const f32x4*)(xg + i + 4);
  short8 v;
#pragma unroll
  for (int j = 0; j < 4; ++j) { v[j] = f2bf(a[j]); v[4 + j] = f2bf(b[j]); }
  *(short8*)(xb + i) = v;
}

// Record format (16B, one per (row, cs)): 8 bf16 = one MFMA A-fragment.
// Step tag (t mod 4) embedded as LSBs of col0 (bit0) and col4 (bit1).
// Poll-passing induction bounds slot staleness to {t, t-2}; bit1 separates.
// NOTE (R14/R15 lesson): the x-part MUST stay between publish and poll in
// program order — it is the equilibrium backoff that makes first-attempt
// polls succeed. Poll-first variants regressed 15-36% with +200MB of
// failed-attempt fetch traffic.

template<int USE_XB>
__global__ __launch_bounds__(NT, 1) void lstm_persist(
    const float* __restrict__ xg, const short* __restrict__ xb,
    const float* __restrict__ Wf, const float* __restrict__ bfv,
    const float* __restrict__ Wi, const float* __restrict__ biv,
    const float* __restrict__ Wc, const float* __restrict__ bcv,
    const float* __restrict__ Wo, const float* __restrict__ bov,
    float* __restrict__ out,
    char* __restrict__ hbc)   // [2][64 rows][64 cs][16B] tagged fragment records
{
  __shared__ short Wl[32 * 1024];    // 64 KB: W slice, [gc][k] bf16, swizzled

  const int tid  = threadIdx.x;
  const int wg   = blockIdx.x;
  const int cs   = wg >> 2;          // column slice 0..63
  const int rc   = wg & 3;           // row cohort 0..3 (16 batch rows)
  const int lane = tid;              // single wave

  // ---- one-time: stage this WG's W slice (transposed to [gc][k], bf16) ----
  {
    const float* Wg4[4] = {Wf, Wi, Wc, Wo};
    const int gc  = tid >> 1;        // 0..31
    const int seg = tid & 1;         // k half of 512
    const float* Wsrc = Wg4[gc >> 3];
    const int col = cs * HCW + (gc & 7);
    for (int kk = 0; kk < 512; ++kk) {
      const int k = seg * 512 + kk;
      *(short*)((char*)Wl + wl_byte(gc, k)) = f2bf(Wsrc[(size_t)k * H_ + col]);
    }
  }

  // Transposed-C lane mapping: lane&15 = batch row, (lane>>4)*4+reg = gatecol.
  const int q    = lane >> 4;        // 0..3
  const int rr   = lane & 15;        // batch row within wave tile
  const int c0   = (q & 1) << 2;     // col-quad base within slice's 8 cols
  const int colq = cs * HCW + c0;    // global col-quad base
  float bF4[4], bI4[4], bG4[4], bO4[4];
#pragma unroll
  for (int r = 0; r < 4; ++r) {
    bF4[r] = bfv[colq + r]; bI4[r] = biv[colq + r];
    bG4[r] = bcv[colq + r]; bO4[r] = bov[colq + r];
  }

  __syncthreads();                   // Wl ready (single wave; effectively free)

  const int rowb = (rc << 4) + rr;   // this lane's batch row
  const int kb8  = q << 3;

  float cst[4] = {0.f, 0.f, 0.f, 0.f};   // cell state: 4 cols of row rowb

  for (int t = 0; t < S_; ++t) {
    const char* hrd = hbc + (t & 1) * (B_ * NCS * 16);
    char*       hwr = hbc + ((t + 1) & 1) * (B_ * NCS * 16);

    f32x4 acc0 = {0.f, 0.f, 0.f, 0.f};   // gatecols [0,16):  f | i
    f32x4 acc1 = {0.f, 0.f, 0.f, 0.f};   // gatecols [16,32): g | o

    // ---- x-part first (no cross-WG dependency; doubles as poll backoff) ----
    if constexpr (USE_XB) {
      const short* xr = xb + (size_t)rowb * S_ * D_ + (size_t)t * D_;
#pragma unroll 4
      for (int ks = 0; ks < 16; ++ks) {
        const int kx = ks * 32 + kb8;
        short8 a = *(const short8*)(xr + kx);   // 16B coalesced bf16, no cvt
        const int kw = 512 + kx;
        short8 b0 = *(const short8*)((const char*)Wl + wl_byte(lane & 15, kw));
        short8 b1 = *(const short8*)((const char*)Wl + wl_byte(16 + (lane & 15), kw));
        acc0 = __builtin_amdgcn_mfma_f32_16x16x32_bf16(b0, a, acc0, 0, 0, 0);
        acc1 = __builtin_amdgcn_mfma_f32_16x16x32_bf16(b1, a, acc1, 0, 0, 0);
      }
    } else {
      const float* xr = xg + (size_t)rowb * S_ * D_ + (size_t)t * D_;
#pragma unroll 4
      for (int ks = 0; ks < 16; ++ks) {
        const int kx = ks * 32 + kb8;
        f32x4 f0 = *(const f32x4*)(xr + kx);
        f32x4 f1 = *(const f32x4*)(xr + kx + 4);
        short8 a;
#pragma unroll
        for (int j = 0; j < 4; ++j) { a[j] = f2bf(f0[j]); a[4 + j] = f2bf(f1[j]); }
        const int kw = 512 + kx;
        short8 b0 = *(const short8*)((const char*)Wl + wl_byte(lane & 15, kw));
        short8 b1 = *(const short8*)((const char*)Wl + wl_byte(16 + (lane & 15), kw));
        acc0 = __builtin_amdgcn_mfma_f32_16x16x32_bf16(b0, a, acc0, 0, 0, 0);
        acc1 = __builtin_amdgcn_mfma_f32_16x16x32_bf16(b1, a, acc1, 0, 0, 0);
      }
    }

    // ---- h-part: poll tagged fragment records (detection == data load).
    //      Lane needs records (rowb, cs = 4*ks + q), ks=0..15: base
    //      rowb*1024 + q*16, stride 64B -> 16 loads, 4 q-groups share 64B
    //      lines per instruction. vmcnt(0) also drains our previous-step
    //      record stores (same-address parity reuse). ----
    {
      const char* rb = hrd + (rowb << 10) + (q << 4);
      const unsigned int t0 = (unsigned int)t;        // bit0 target
      const unsigned int t1 = (unsigned int)t >> 1;   // bit1 target
      U128 rc0, rc1, rc2, rc3, rc4, rc5, rc6, rc7,
           rc8, rc9, rc10, rc11, rc12, rc13, rc14, rc15;
      while (true) {
        asm volatile(
          "global_load_dwordx4 %[r0], %[p], off sc1\n\t"
          "global_load_dwordx4 %[r1], %[p], off offset:64 sc1\n\t"
          "global_load_dwordx4 %[r2], %[p], off offset:128 sc1\n\t"
          "global_load_dwordx4 %[r3], %[p], off offset:192 sc1\n\t"
          "global_load_dwordx4 %[r4], %[p], off offset:256 sc1\n\t"
          "global_load_dwordx4 %[r5], %[p], off offset:320 sc1\n\t"
          "global_load_dwordx4 %[r6], %[p], off offset:384 sc1\n\t"
          "global_load_dwordx4 %[r7], %[p], off offset:448 sc1\n\t"
          "global_load_dwordx4 %[r8], %[p], off offset:512 sc1\n\t"
          "global_load_dwordx4 %[r9], %[p], off offset:576 sc1\n\t"
          "global_load_dwordx4 %[r10], %[p], off offset:640 sc1\n\t"
          "global_load_dwordx4 %[r11], %[p], off offset:704 sc1\n\t"
          "global_load_dwordx4 %[r12], %[p], off offset:768 sc1\n\t"
          "global_load_dwordx4 %[r13], %[p], off offset:832 sc1\n\t"
          "global_load_dwordx4 %[r14], %[p], off offset:896 sc1\n\t"
          "global_load_dwordx4 %[r15], %[p], off offset:960 sc1\n\t"
          "s_waitcnt vmcnt(0)"
          : [r0]"=&v"(rc0.s), [r1]"=&v"(rc1.s), [r2]"=&v"(rc2.s),
            [r3]"=&v"(rc3.s), [r4]"=&v"(rc4.s), [r5]"=&v"(rc5.s),
            [r6]"=&v"(rc6.s), [r7]"=&v"(rc7.s), [r8]"=&v"(rc8.s),
            [r9]"=&v"(rc9.s), [r10]"=&v"(rc10.s), [r11]"=&v"(rc11.s),
            [r12]"=&v"(rc12.s), [r13]"=&v"(rc13.s), [r14]"=&v"(rc14.s),
            [r15]"=&v"(rc15.s)
          : [p]"v"(rb)
          : "memory");
        // tag bits: bit0 = LSB of col0 (w[0]), bit1 = LSB of col4 (w[2])
#define TCHK(R) ( ((R.w[0] ^ t0) & 1u) | ((R.w[2] ^ t1) & 1u) )
        const unsigned int bad =
            TCHK(rc0)  | TCHK(rc1)  | TCHK(rc2)  | TCHK(rc3)  |
            TCHK(rc4)  | TCHK(rc5)  | TCHK(rc6)  | TCHK(rc7)  |
            TCHK(rc8)  | TCHK(rc9)  | TCHK(rc10) | TCHK(rc11) |
            TCHK(rc12) | TCHK(rc13) | TCHK(rc14) | TCHK(rc15);
#undef TCHK
        if (__all((int)(bad == 0u))) break;
      }

      // Two independent 8-deep MFMA chains per acc (halve latency exposure).
      f32x4 acc0b = {0.f, 0.f, 0.f, 0.f};
      f32x4 acc1b = {0.f, 0.f, 0.f, 0.f};
#define HSTEP(KS, RA, A0, A1)                                                  \
      {                                                                        \
        const int k0_ = (KS) * 32 + kb8;                                       \
        short8 b0_ = *(const short8*)((const char*)Wl + wl_byte(lane & 15, k0_)); \
        short8 b1_ = *(const short8*)((const char*)Wl + wl_byte(16 + (lane & 15), k0_)); \
        A0 = __builtin_amdgcn_mfma_f32_16x16x32_bf16(b0_, RA.s, A0, 0, 0, 0);  \
        A1 = __builtin_amdgcn_mfma_f32_16x16x32_bf16(b1_, RA.s, A1, 0, 0, 0);  \
      }
      HSTEP(0,  rc0,  acc0,  acc1)  HSTEP(1,  rc1,  acc0b, acc1b)
      HSTEP(2,  rc2,  acc0,  acc1)  HSTEP(3,  rc3,  acc0b, acc1b)
      HSTEP(4,  rc4,  acc0,  acc1)  HSTEP(5,  rc5,  acc0b, acc1b)
      HSTEP(6,  rc6,  acc0,  acc1)  HSTEP(7,  rc7,  acc0b, acc1b)
      HSTEP(8,  rc8,  acc0,  acc1)  HSTEP(9,  rc9,  acc0b, acc1b)
      HSTEP(10, rc10, acc0,  acc1)  HSTEP(11, rc11, acc0b, acc1b)
      HSTEP(12, rc12, acc0,  acc1)  HSTEP(13, rc13, acc0b, acc1b)
      HSTEP(14, rc14, acc0,  acc1)  HSTEP(15, rc15, acc0b, acc1b)
#undef HSTEP
#pragma unroll
      for (int j = 0; j < 4; ++j) { acc0[j] += acc0b[j]; acc1[j] += acc1b[j]; }
    }

    // ---- epilogue: exchange f<->i / g<->o halves across lane^32 ----
    f32x4 x0, x1;
#pragma unroll
    for (int j = 0; j < 4; ++j) {
      x0[j] = __shfl_xor(acc0[j], 32);
      x1[j] = __shfl_xor(acc1[j], 32);
    }
    const bool lo = (q < 2);
    float hv[4];
#pragma unroll
    for (int r = 0; r < 4; ++r) {
      const float sF = (lo ? acc0[r] : x0[r]) + bF4[r];
      const float sI = (lo ? x0[r] : acc0[r]) + bI4[r];
      const float sG = (lo ? acc1[r] : x1[r]) + bG4[r];
      const float sO = (lo ? x1[r] : acc1[r]) + bO4[r];
      const float fg = sigm(sF);
      const float ig = sigm(sI);
      const float gg = tanh_(sG);
      const float og = sigm(sO);
      const float cn = cst[r] * fg + gg * ig;
      cst[r] = cn;
      hv[r] = og * tanh_(cn);
    }

    // ---- record broadcast: merge the two col-quads of this cs across
    //      lane^16, embed tag bits, ONE 16B store per row (q==0 lanes) ----
    unsigned long long hp8;
    {
      unsigned int l32 = (unsigned int)(unsigned short)f2bf(hv[0])
                       | ((unsigned int)(unsigned short)f2bf(hv[1]) << 16);
      unsigned int h32 = (unsigned int)(unsigned short)f2bf(hv[2])
                       | ((unsigned int)(unsigned short)f2bf(hv[3]) << 16);
      hp8 = (unsigned long long)l32 | ((unsigned long long)h32 << 32);
    }
    unsigned long long other = __shfl_xor(hp8, 16);  // partner quad, same row
    if (q == 0 && t < S_ - 1) {
      const unsigned int tag = (unsigned int)(t + 1);
      U128 u;
      u.w[0] = ((unsigned int)hp8 & ~1u) | (tag & 1u);          // col0 LSB=bit0
      u.w[1] = (unsigned int)(hp8 >> 32);
      u.w[2] = ((unsigned int)other & ~1u) | ((tag >> 1) & 1u); // col4 LSB=bit1
      u.w[3] = (unsigned int)(other >> 32);
      store_b128_dev(hwr + (rowb << 10) + (cs << 4), u.s);
    }

    if (lo) {
      // ---- out: one 16B store per lane (4 consecutive cols of row rowb),
      //      full-precision f32 (tag bits only live in the bf16 broadcast) ----
      f32x4 hv4;
#pragma unroll
      for (int r = 0; r < 4; ++r) hv4[r] = hv[r];
      *(f32x4*)(out + (size_t)rowb * ((size_t)S_ * H_) + (size_t)t * H_ + colq) = hv4;
      if (t == S_ - 1) {
        f32x4 c4;
#pragma unroll
        for (int r = 0; r < 4; ++r) c4[r] = cst[r];
        *(f32x4*)(out + (size_t)B_ * S_ * H_ + (size_t)rowb * H_ + colq) = hv4;
        *(f32x4*)(out + (size_t)B_ * S_ * H_ + (size_t)B_ * H_
                      + (size_t)rowb * H_ + colq) = c4;
      }
    }
    // No drain, no flag, no barrier: tags ride with the data.
  }
}

extern "C" void kernel_launch(void* const* d_in, const int* in_sizes, int n_in,
                              void* d_out, int out_size, void* d_ws, size_t ws_size,
                              hipStream_t stream) {
  (void)in_sizes; (void)n_in; (void)out_size;
  const float* x  = (const float*)d_in[0];
  const float* Wf = (const float*)d_in[1];
  const float* bf = (const float*)d_in[2];
  const float* Wi = (const float*)d_in[3];
  const float* bi = (const float*)d_in[4];
  const float* Wc = (const float*)d_in[5];
  const float* bc = (const float*)d_in[6];
  const float* Wo = (const float*)d_in[7];
  const float* bo = (const float*)d_in[8];
  float* out = (float*)d_out;

  char* hbc = (char*)d_ws;   // 128 KB: [2][64][64][16B] tagged fragment records

  const size_t XB_OFF   = (size_t)1 << 20;                        // 1 MB
  const size_t XB_BYTES = (size_t)B_ * S_ * D_ * sizeof(short);   // 64 MB

  // zero both parities: tag bits 0 == t=0 mod 4, data 0 == h_0; captured in
  // the graph, so every replay starts from a clean state.
  hipMemsetAsync(d_ws, 0, 2 * B_ * NCS * 16, stream);

  if (ws_size >= XB_OFF + XB_BYTES) {
    short* xb = (short*)((char*)d_ws + XB_OFF);
    lstm_xprep<<<dim3((B_ * S_ * D_) / (256 * 8)), dim3(256), 0, stream>>>(x, xb);
    lstm_persist<1><<<dim3(NWG), dim3(NT), 0, stream>>>(
        x, xb, Wf, bf, Wi, bi, Wc, bc, Wo, bo, out, hbc);
  } else {
    lstm_persist<0><<<dim3(NWG), dim3(NT), 0, stream>>>(
        x, nullptr, Wf, bf, Wi, bi, Wc, bc, Wo, bo, out, hbc);
  }
}